// Round 6
// baseline (247.934 us; speedup 1.0000x reference)
//
#include <hip/hip_runtime.h>
#include <hip/hip_bf16.h>

// FEAT=EMB=HID=64, VOCAB=32, N_GRAPHS=64. N,E from in_sizes.
// R6: transform-first. R7: binned CSR. R9: padded CSR + mask-free gather.
// R11: fp8 e4m3 gather table (64B rows = 1 line), quarter-wave dword gather.
// R13/R14: gemm1 fused into binning kernel; B-frags self-built from fp32.
// R17: head_kernel rewrite (LDS-staged weights, reg-blocked, parallel softmax).
// R18 REVERTED (fusions serialized 16 nodes/wave -> latency-bound 137us).
// R19: two-node-interleaved aggregate (8 gather loads in flight). 272->264us.
// R20 REVERTED to 2-node (4-node = +13% padded work, no latency win left).
// R21: per-node wave-uniform tail guards + 32-bit saddr. 275.6->246.5us.
// R22: (a) f32x2 accumulators -> v_pk_add_f32 (16 scalar adds -> 8 pk adds
// per 16-edge group; VALUBusy was ~50%); (b) bucket-load mask now uses TRUE
// degree so pad slots are never read -> finalize_csr's serial pad-tail write
// loop (~800K scattered stores) deleted. Bit-identical math both changes.

typedef __attribute__((ext_vector_type(8))) short short8;
typedef __attribute__((ext_vector_type(4))) float f32x4;
typedef __attribute__((ext_vector_type(2))) float f32x2;

#define RB 9            // 512 nodes per coarse bin
#define MAXBINS 256     // N <= 131072
#define CAP 12288       // coarse per-bin capacity
#define BCAP 14336      // padded per-bin bucket capacity
#define CHUNK 8192      // edges per bin block

__device__ inline float bf2f(unsigned short h) {
    return __uint_as_float(((unsigned int)h) << 16);
}
__device__ inline float bflo(unsigned int u) { return __uint_as_float(u << 16); }
__device__ inline float bfhi(unsigned int u) { return __uint_as_float(u & 0xffff0000u); }
__device__ inline unsigned short f2bf(float f) {
    unsigned int u = __float_as_uint(f);
    u = (u + 0x7fffu + ((u >> 16) & 1u)) >> 16;  // RNE
    return (unsigned short)u;
}

// Self-build MFMA B-fragments from fp32 W (cols 0..63) and R (cols 64..127).
__device__ inline void build_bfrag(const float* __restrict__ W,
                                   const float* __restrict__ R,
                                   int q, int mm, short8 bfrag[8][2]) {
#pragma unroll
    for (int t = 0; t < 8; ++t) {
        const int n = t * 16 + mm;
        const float* P = (n < 64) ? (W + n) : (R + n - 64);
#pragma unroll
        for (int c = 0; c < 2; ++c) {
#pragma unroll
            for (int j = 0; j < 8; ++j) {
                const int k = c * 32 + q * 8 + j;
                bfrag[t][c][j] = (short)f2bf(P[k * 64]);
            }
        }
    }
}

// fp8 epilogue store: lanes mm%4==0 pack 4 n-columns into one dword.
__device__ inline void store_xw_fp8(unsigned char* __restrict__ xw8, int rowbase, int q,
                                    int t, int mm, const f32x4& accT, int N) {
#pragma unroll
    for (int r = 0; r < 4; ++r) {
        const float v0 = accT[r];
        const float v1 = __shfl_down(v0, 1);
        const float v2 = __shfl_down(v0, 2);
        const float v3 = __shfl_down(v0, 3);
        const int orow = rowbase + q * 4 + r;
        if (!(mm & 3) && orow < N) {
            unsigned int u = (unsigned int)__builtin_amdgcn_cvt_pk_fp8_f32(v0, v1, 0, false);
            u = (unsigned int)__builtin_amdgcn_cvt_pk_fp8_f32(v2, v3, (int)u, true);
            *(unsigned int*)&xw8[(size_t)orow * 64 + t * 16 + mm] = u;
        }
    }
}

// ---------------- K1: bin edges (blocks [0,nbBin)) + gemm1 (rest) -----------
__global__ __launch_bounds__(256) void bin_gemm1(const int* __restrict__ src,
                                                 const int* __restrict__ dst,
                                                 unsigned int* __restrict__ coarse,
                                                 int* __restrict__ gcur,
                                                 int E, int BINS, int nbBin,
                                                 const float* __restrict__ x,
                                                 const float* __restrict__ W1,
                                                 const float* __restrict__ R1,
                                                 const float* __restrict__ bias,
                                                 unsigned char* __restrict__ xw8,
                                                 unsigned short* __restrict__ xrb,
                                                 int N) {
    __shared__ int cnt[MAXBINS];
    __shared__ int incl[MAXBINS];
    __shared__ int bstart[MAXBINS];
    __shared__ int bcur[MAXBINS];
    __shared__ int gbase[MAXBINS];
    __shared__ unsigned int stage[CHUNK];
    __shared__ unsigned char binOf[CHUNK];

    const int tid = threadIdx.x;
    if (blockIdx.x >= (unsigned)nbBin) {
        // ---- gemm1 branch: xw8/xrb = x @ [W1|R1] (+b1 in R half) ----
        const int gb = blockIdx.x - nbBin;
        if (gb == 0 && tid < 16)  // zero fp8 row N (dummy target)
            *(unsigned int*)&xw8[(size_t)N * 64 + tid * 4] = 0u;

        const int lane = tid & 63;
        const int q = lane >> 4;
        const int mm = lane & 15;

        short8 bfrag[8][2];
        build_bfrag(W1, R1, q, mm, bfrag);
        float bv[4];
#pragma unroll
        for (int tt = 0; tt < 4; ++tt) bv[tt] = bias[tt * 16 + mm];

        const int wid = tid >> 6;
        const int gw = gb * 4 + wid;
        const int nw = 1024 * 4;
        const int ntiles = N >> 4;

        for (int tile = gw; tile < ntiles; tile += nw) {
            const int row0 = tile << 4;
            const float* ap = &x[(size_t)(row0 + mm) * 64 + q * 8];
            const float4 f0 = *(const float4*)ap;
            const float4 f1 = *(const float4*)(ap + 4);
            const float4 f2 = *(const float4*)(ap + 32);
            const float4 f3 = *(const float4*)(ap + 36);
            short8 a0, a1;
            a0[0] = (short)f2bf(f0.x); a0[1] = (short)f2bf(f0.y);
            a0[2] = (short)f2bf(f0.z); a0[3] = (short)f2bf(f0.w);
            a0[4] = (short)f2bf(f1.x); a0[5] = (short)f2bf(f1.y);
            a0[6] = (short)f2bf(f1.z); a0[7] = (short)f2bf(f1.w);
            a1[0] = (short)f2bf(f2.x); a1[1] = (short)f2bf(f2.y);
            a1[2] = (short)f2bf(f2.z); a1[3] = (short)f2bf(f2.w);
            a1[4] = (short)f2bf(f3.x); a1[5] = (short)f2bf(f3.y);
            a1[6] = (short)f2bf(f3.z); a1[7] = (short)f2bf(f3.w);
            f32x4 acc[8];
#pragma unroll
            for (int t = 0; t < 8; ++t) {
                acc[t] = (f32x4){0.f, 0.f, 0.f, 0.f};
                acc[t] = __builtin_amdgcn_mfma_f32_16x16x32_bf16(a0, bfrag[t][0], acc[t], 0, 0, 0);
                acc[t] = __builtin_amdgcn_mfma_f32_16x16x32_bf16(a1, bfrag[t][1], acc[t], 0, 0, 0);
            }
#pragma unroll
            for (int t = 0; t < 4; ++t) store_xw_fp8(xw8, row0, q, t, mm, acc[t], N);
#pragma unroll
            for (int t = 4; t < 8; ++t) {
#pragma unroll
                for (int r = 0; r < 4; ++r) {
                    const float v = acc[t][r] + bv[t - 4];
                    const float vn = __shfl_down(v, 1);
                    if (!(mm & 1)) {
                        const unsigned int u = (unsigned int)f2bf(v) | ((unsigned int)f2bf(vn) << 16);
                        *(unsigned int*)&xrb[(size_t)(row0 + q * 4 + r) * 64 + (t - 4) * 16 + mm] = u;
                    }
                }
            }
        }
        return;
    }

    // ---- binning branch ----
    const int chunk0 = blockIdx.x * CHUNK;
    int myS[32], myD[32];
#pragma unroll
    for (int k = 0; k < 32; ++k) {
        const int idx = chunk0 + k * 256 + tid;
        if (idx < E) { myS[k] = src[idx]; myD[k] = dst[idx]; }
        else myD[k] = -1;
    }
    cnt[tid] = 0;
    __syncthreads();
#pragma unroll
    for (int k = 0; k < 32; ++k)
        if (myD[k] >= 0) atomicAdd(&cnt[myD[k] >> RB], 1);
    __syncthreads();
    incl[tid] = cnt[tid];
    __syncthreads();
    for (int off = 1; off < 256; off <<= 1) {
        int t = (tid >= off) ? incl[tid - off] : 0;
        __syncthreads();
        incl[tid] += t;
        __syncthreads();
    }
    bstart[tid] = incl[tid] - cnt[tid];
    bcur[tid] = incl[tid] - cnt[tid];
    __syncthreads();
#pragma unroll
    for (int k = 0; k < 32; ++k) {
        if (myD[k] >= 0) {
            const int b = myD[k] >> RB;
            const int pos = atomicAdd(&bcur[b], 1);
            stage[pos] = (unsigned int)myS[k] | ((unsigned int)(myD[k] & ((1 << RB) - 1)) << 17);
            binOf[pos] = (unsigned char)b;
        }
    }
    __syncthreads();
    if (tid < BINS && cnt[tid] > 0)
        gbase[tid] = tid * CAP + atomicAdd(&gcur[tid], cnt[tid]);
    __syncthreads();
    int total = E - chunk0;
    if (total > CHUNK) total = CHUNK;
    for (int idx = tid; idx < total; idx += 256) {
        const int b = binOf[idx];
        coarse[gbase[b] + (idx - bstart[b])] = stage[idx];
    }
}

// ---------------- K2: finalize padded CSR (one block per bin) ---------------
// R22: pad-tail writes removed — aggregate masks bucket loads by TRUE degree,
// so pad slots are never read. Offsets stay 16-padded for group alignment.
__global__ __launch_bounds__(256) void finalize_csr(const unsigned int* __restrict__ coarse,
                                                    const int* __restrict__ gcur,
                                                    int* __restrict__ bucket,
                                                    int* __restrict__ pstart,
                                                    int* __restrict__ degarr,
                                                    int N, int BINS) {
    __shared__ int ncnt[512];
    __shared__ int pexcl[512];
    __shared__ int ncur[512];
    __shared__ int s2[256];

    const int tid = threadIdx.x;
    const int b = blockIdx.x;
    const int cb = gcur[b];
    const int base = b * BCAP;
    const unsigned int* reg = coarse + (size_t)b * CAP;
    const int node0 = b << RB;
    int nloc = N - node0;
    if (nloc > 512) nloc = 512;

    ncnt[tid] = 0; ncnt[tid + 256] = 0;
    __syncthreads();
    for (int idx = tid; idx < cb; idx += 256)
        atomicAdd(&ncnt[reg[idx] >> 17], 1);
    __syncthreads();
    const int p0 = (ncnt[2 * tid] + 15) & ~15;
    const int p1 = (ncnt[2 * tid + 1] + 15) & ~15;
    s2[tid] = p0 + p1;
    __syncthreads();
    for (int off = 1; off < 256; off <<= 1) {
        int t = (tid >= off) ? s2[tid - off] : 0;
        __syncthreads();
        s2[tid] += t;
        __syncthreads();
    }
    const int pairExcl = s2[tid] - (p0 + p1);
    pexcl[2 * tid] = pairExcl;
    pexcl[2 * tid + 1] = pairExcl + p0;
    ncur[2 * tid] = pairExcl;
    ncur[2 * tid + 1] = pairExcl + p0;
    __syncthreads();
    for (int i = tid; i < nloc; i += 256) {
        pstart[node0 + i] = base + pexcl[i];
        degarr[node0 + i] = ncnt[i];
    }
    for (int idx = tid; idx < cb; idx += 256) {
        const unsigned int e = reg[idx];
        const int p = atomicAdd(&ncur[e >> 17], 1);
        bucket[base + p] = (int)(e & 0x1FFFFu);
    }
}

// ---------------- K3/K5: aggregate: out = relu(mean_j xW[j] + xRb[i]) -------
// R21: two nodes (i, i+nw) interleaved; per-node wave-uniform tail guards;
// 32-bit saddr addressing. R22: f32x2 accumulators (v_pk_add_f32) + bucket
// load mask by TRUE degree (lanes >= dg carry s=N, pad slots never read).
__global__ __launch_bounds__(256) void aggregate(const unsigned char* __restrict__ xw8,
                                                 const unsigned short* __restrict__ xrb,
                                                 const int* __restrict__ pstart,
                                                 const int* __restrict__ degarr,
                                                 const int* __restrict__ bucket,
                                                 unsigned short* __restrict__ outb,
                                                 int N) {
    const int lane = threadIdx.x & 63;
    const int quarter = lane >> 4;
    const int fl = lane & 15;
    const int wid = threadIdx.x >> 6;
    const int gw = blockIdx.x * 4 + wid;
    const int nw = gridDim.x * 4;
    const unsigned flo = (unsigned)(fl << 2);

    for (int i = gw; i < N; i += 2 * nw) {
        const int iA = i;
        const int iB = i + nw;
        const bool hasB = iB < N;
        const int r0A = pstart[iA];
        const int dgA = degarr[iA];
        int r0B = r0A, dgB = 0;
        if (hasB) { r0B = pstart[iB]; dgB = degarr[iB]; }
        const int pdA = (dgA + 15) & ~15;
        const int pdB = (dgB + 15) & ~15;
        const int pdM = pdA > pdB ? pdA : pdB;

        f32x2 aAlo = {0.f, 0.f}, aAhi = {0.f, 0.f};
        f32x2 aBlo = {0.f, 0.f}, aBhi = {0.f, 0.f};
        for (int base = 0; base < pdM; base += 64) {
            const int remA = pdA - base;     // padded remainder: group guard
            const int remB = pdB - base;
            const int trmA = dgA - base;     // true remainder: bucket mask
            const int trmB = dgB - base;
            int sA = N, sB = N;
            if (trmA > 0 && lane < trmA)
                sA = *(const int*)((const char*)bucket + ((unsigned)(r0A + base + lane) << 2));
            if (trmB > 0 && lane < trmB)
                sB = *(const int*)((const char*)bucket + ((unsigned)(r0B + base + lane) << 2));
            const int mxA = remA < 64 ? remA : 64;
            const int mxB = remB < 64 ? remB : 64;
            int mx = pdM - base;
            if (mx > 64) mx = 64;
            for (int t = 0; t < mx; t += 16) {
                const bool doA = t < mxA;   // wave-uniform
                const bool doB = t < mxB;   // wave-uniform
                unsigned int uA[4], uB[4];
                if (doA) {
#pragma unroll
                    for (int p = 0; p < 4; ++p) {
                        const unsigned rr = (unsigned)__shfl(sA, t + 4 * p + quarter);
                        uA[p] = *(const unsigned int*)(xw8 + ((rr << 6) | flo));
                    }
                }
                if (doB) {
#pragma unroll
                    for (int p = 0; p < 4; ++p) {
                        const unsigned rr = (unsigned)__shfl(sB, t + 4 * p + quarter);
                        uB[p] = *(const unsigned int*)(xw8 + ((rr << 6) | flo));
                    }
                }
                if (doA) {
#pragma unroll
                    for (int p = 0; p < 4; ++p) {
                        aAlo += __builtin_amdgcn_cvt_pk_f32_fp8(uA[p], false);
                        aAhi += __builtin_amdgcn_cvt_pk_f32_fp8(uA[p], true);
                    }
                }
                if (doB) {
#pragma unroll
                    for (int p = 0; p < 4; ++p) {
                        aBlo += __builtin_amdgcn_cvt_pk_f32_fp8(uB[p], false);
                        aBhi += __builtin_amdgcn_cvt_pk_f32_fp8(uB[p], true);
                    }
                }
            }
        }
        float aA0 = aAlo.x, aA1 = aAlo.y, aA2 = aAhi.x, aA3 = aAhi.y;
        float aB0 = aBlo.x, aB1 = aBlo.y, aB2 = aBhi.x, aB3 = aBhi.y;
        aA0 += __shfl_xor(aA0, 16); aA1 += __shfl_xor(aA1, 16);
        aA2 += __shfl_xor(aA2, 16); aA3 += __shfl_xor(aA3, 16);
        aA0 += __shfl_xor(aA0, 32); aA1 += __shfl_xor(aA1, 32);
        aA2 += __shfl_xor(aA2, 32); aA3 += __shfl_xor(aA3, 32);
        aB0 += __shfl_xor(aB0, 16); aB1 += __shfl_xor(aB1, 16);
        aB2 += __shfl_xor(aB2, 16); aB3 += __shfl_xor(aB3, 16);
        aB0 += __shfl_xor(aB0, 32); aB1 += __shfl_xor(aB1, 32);
        aB2 += __shfl_xor(aB2, 32); aB3 += __shfl_xor(aB3, 32);

        if (quarter == 0) {
            const float invA = 1.0f / (float)(dgA > 0 ? dgA : 1);
            const uint2 urA = *(const uint2*)&xrb[(size_t)iA * 64 + fl * 4];
            const float o0 = fmaxf(aA0 * invA + bflo(urA.x), 0.f);
            const float o1 = fmaxf(aA1 * invA + bfhi(urA.x), 0.f);
            const float o2 = fmaxf(aA2 * invA + bflo(urA.y), 0.f);
            const float o3 = fmaxf(aA3 * invA + bfhi(urA.y), 0.f);
            uint2 w;
            w.x = (unsigned int)f2bf(o0) | ((unsigned int)f2bf(o1) << 16);
            w.y = (unsigned int)f2bf(o2) | ((unsigned int)f2bf(o3) << 16);
            *(uint2*)&outb[(size_t)iA * 64 + fl * 4] = w;
            if (hasB) {
                const float invB = 1.0f / (float)(dgB > 0 ? dgB : 1);
                const uint2 urB = *(const uint2*)&xrb[(size_t)iB * 64 + fl * 4];
                const float p0 = fmaxf(aB0 * invB + bflo(urB.x), 0.f);
                const float p1 = fmaxf(aB1 * invB + bfhi(urB.x), 0.f);
                const float p2 = fmaxf(aB2 * invB + bflo(urB.y), 0.f);
                const float p3 = fmaxf(aB3 * invB + bfhi(urB.y), 0.f);
                uint2 w2;
                w2.x = (unsigned int)f2bf(p0) | ((unsigned int)f2bf(p1) << 16);
                w2.y = (unsigned int)f2bf(p2) | ((unsigned int)f2bf(p3) << 16);
                *(uint2*)&outb[(size_t)iB * 64 + fl * 4] = w2;
            }
        }
    }
}

// ---------------- K4: gemm layer 2 (bf16 A from h1, self-built B) -----------
__global__ __launch_bounds__(256) void gemm_xwr2(const unsigned short* __restrict__ xin,
                                                 const float* __restrict__ W2,
                                                 const float* __restrict__ R2,
                                                 const float* __restrict__ bias,
                                                 unsigned char* __restrict__ xw8,
                                                 unsigned short* __restrict__ xrb,
                                                 int M) {
    if (blockIdx.x == 0 && threadIdx.x < 16)
        *(unsigned int*)&xw8[(size_t)M * 64 + threadIdx.x * 4] = 0u;

    const int lane = threadIdx.x & 63;
    const int q = lane >> 4;
    const int mm = lane & 15;

    short8 bfrag[8][2];
    build_bfrag(W2, R2, q, mm, bfrag);
    float bv[4];
#pragma unroll
    for (int tt = 0; tt < 4; ++tt) bv[tt] = bias[tt * 16 + mm];

    const int wid = threadIdx.x >> 6;
    const int gw = blockIdx.x * 4 + wid;
    const int nw = gridDim.x * 4;
    const int ntiles = M >> 4;

    for (int tile = gw; tile < ntiles; tile += nw) {
        const int row0 = tile << 4;
        const short8 a0 = *(const short8*)&xin[(size_t)(row0 + mm) * 64 + q * 8];
        const short8 a1 = *(const short8*)&xin[(size_t)(row0 + mm) * 64 + 32 + q * 8];
        f32x4 acc[8];
#pragma unroll
        for (int t = 0; t < 8; ++t) {
            acc[t] = (f32x4){0.f, 0.f, 0.f, 0.f};
            acc[t] = __builtin_amdgcn_mfma_f32_16x16x32_bf16(a0, bfrag[t][0], acc[t], 0, 0, 0);
            acc[t] = __builtin_amdgcn_mfma_f32_16x16x32_bf16(a1, bfrag[t][1], acc[t], 0, 0, 0);
        }
#pragma unroll
        for (int t = 0; t < 4; ++t) store_xw_fp8(xw8, row0, q, t, mm, acc[t], M);
#pragma unroll
        for (int t = 4; t < 8; ++t) {
#pragma unroll
            for (int r = 0; r < 4; ++r) {
                const float v = acc[t][r] + bv[t - 4];
                const float vn = __shfl_down(v, 1);
                if (!(mm & 1)) {
                    const unsigned int u = (unsigned int)f2bf(v) | ((unsigned int)f2bf(vn) << 16);
                    *(unsigned int*)&xrb[(size_t)(row0 + q * 4 + r) * 64 + (t - 4) * 16 + mm] = u;
                }
            }
        }
    }
}

// ---------------- K6: pooling (4 blocks per graph, atomic sums) -------------
__global__ __launch_bounds__(256) void pool_kernel(const unsigned short* __restrict__ h,
                                                   const int* __restrict__ batch,
                                                   float* __restrict__ gsum, int N) {
    __shared__ float red[16][64];
    __shared__ int bnds[2];
    const int gph = blockIdx.x >> 2;
    const int part = blockIdx.x & 3;
    if (threadIdx.x < 2) {
        const int target = gph + threadIdx.x;
        int lo = 0, hi = N;
        while (lo < hi) {
            int mid = (lo + hi) >> 1;
            if (batch[mid] < target) lo = mid + 1; else hi = mid;
        }
        bnds[threadIdx.x] = lo;
    }
    __syncthreads();
    const int r0 = bnds[0], tot = bnds[1] - bnds[0];
    const int pr0 = r0 + (tot * part) / 4;
    const int pr1 = r0 + (tot * (part + 1)) / 4;
    const int f = threadIdx.x & 15;
    const int r = threadIdx.x >> 4;
    float4 acc = {0.f, 0.f, 0.f, 0.f};
    for (int row = pr0 + r; row < pr1; row += 16) {
        const ushort4 v = *(const ushort4*)&h[(size_t)row * 64 + f * 4];
        acc.x += bf2f(v.x); acc.y += bf2f(v.y);
        acc.z += bf2f(v.z); acc.w += bf2f(v.w);
    }
    red[r][f * 4 + 0] = acc.x; red[r][f * 4 + 1] = acc.y;
    red[r][f * 4 + 2] = acc.z; red[r][f * 4 + 3] = acc.w;
    __syncthreads();
    if (threadIdx.x < 64) {
        float s = 0.f;
        for (int j = 0; j < 16; ++j) s += red[j][threadIdx.x];
        atomicAdd(&gsum[gph * 64 + threadIdx.x], s);
    }
}

// ---------------- K7: heads (normalize gsum by counts; R18-verified) --------
__global__ __launch_bounds__(256) void head_kernel(const float* __restrict__ gsum,
                                                   const int* __restrict__ batch,
                                                   const float* __restrict__ Wh,
                                                   const float* __restrict__ bh,
                                                   const float* __restrict__ Wc,
                                                   const float* __restrict__ bc,
                                                   const float* __restrict__ Wo,
                                                   const float* __restrict__ bo,
                                                   float* __restrict__ out, int N) {
    __shared__ float pm[4096];   // pooled; reused for lg[2048] in phase 2/3
    __shared__ float Ws[4096];   // Wh; reused for Wo[2048] in phase 2
    __shared__ float Cs[4096];   // Wc
    __shared__ float hid[4096];
    __shared__ int bnds[65];
    const int t = threadIdx.x;

    // Phase 0a: graph bounds via binary search on sorted batch.
    if (t < 65) {
        int lo = 0, hi = N;
        while (lo < hi) {
            int mid = (lo + hi) >> 1;
            if (batch[mid] < t) lo = mid + 1; else hi = mid;
        }
        bnds[t] = lo;
    }
    __syncthreads();
    // Phase 0b: stage pooled (= gsum/cnt) + Wh + Wc (float4, coalesced).
    for (int idx = t; idx < 1024; idx += 256) {
        const int g = idx >> 4;
        const int c = bnds[g + 1] - bnds[g];
        const float inv = 1.0f / (float)(c > 0 ? c : 1);
        float4 v = ((const float4*)gsum)[idx];
        v.x *= inv; v.y *= inv; v.z *= inv; v.w *= inv;
        ((float4*)pm)[idx] = v;
        ((float4*)Ws)[idx] = ((const float4*)Wh)[idx];
        ((float4*)Cs)[idx] = ((const float4*)Wc)[idx];
    }
    __syncthreads();

    // Phase 1: hidden/cell. Wave w owns 16 graphs, lane l owns col o=l.
    const int w = t >> 6;
    const int l = t & 63;
    const float bhv = bh[l], bcv = bc[l];
    float ah[16], ac[16];
#pragma unroll
    for (int i = 0; i < 16; ++i) { ah[i] = bhv; ac[i] = bcv; }
    const float* pmw = pm + ((w << 4) << 6);
#pragma unroll 4
    for (int k = 0; k < 64; ++k) {
        const float wv = Ws[(k << 6) + l];
        const float cv = Cs[(k << 6) + l];
#pragma unroll
        for (int i = 0; i < 16; ++i) {
            const float p = pmw[(i << 6) + k];
            ah[i] = fmaf(p, wv, ah[i]);
            ac[i] = fmaf(p, cv, ac[i]);
        }
    }
#pragma unroll
    for (int i = 0; i < 16; ++i) {
        const int g = (w << 4) + i;
        hid[(g << 6) + l] = ah[i];
        out[2048 + (g << 6) + l] = ah[i];
        out[6144 + (g << 6) + l] = ac[i];
    }
    __syncthreads();
    // Stage Wo over Ws (reads of Ws are done).
    for (int idx = t; idx < 512; idx += 256)
        ((float4*)Ws)[idx] = ((const float4*)Wo)[idx];
    __syncthreads();

    // Phase 2: logits[g][v] = hid[g] . Wo[:,v] + bo[v]; 8 graphs per thread.
    const int v = l & 31;
    const int gh = l >> 5;                // 0 or 1
    const int g0 = ((w << 1) + gh) << 3;  // 8 consecutive graphs
    const float bov = bo[v];
    float lgacc[8];
#pragma unroll
    for (int i = 0; i < 8; ++i) lgacc[i] = bov;
#pragma unroll 4
    for (int k = 0; k < 64; ++k) {
        const float wv = Ws[(k << 5) + v];
#pragma unroll
        for (int i = 0; i < 8; ++i)
            lgacc[i] = fmaf(hid[((g0 + i) << 6) + k], wv, lgacc[i]);
    }
    float* lg = pm;  // reuse pm (pooled reads are done)
#pragma unroll
    for (int i = 0; i < 8; ++i) lg[((g0 + i) << 5) + v] = lgacc[i];
    __syncthreads();

    // Phase 3: log_softmax, 4 threads per graph (8 vocab each), shfl reduce.
    const int g = t >> 2;
    const int vs = (t & 3) << 3;
    const float* row = lg + (g << 5);
    float mx = -3.4e38f;
#pragma unroll
    for (int j = 0; j < 8; ++j) mx = fmaxf(mx, row[vs + j]);
    mx = fmaxf(mx, __shfl_xor(mx, 1));
    mx = fmaxf(mx, __shfl_xor(mx, 2));
    float s = 0.f;
#pragma unroll
    for (int j = 0; j < 8; ++j) s += __expf(row[vs + j] - mx);
    s += __shfl_xor(s, 1);
    s += __shfl_xor(s, 2);
    const float lse = mx + __logf(s);
#pragma unroll
    for (int j = 0; j < 8; ++j) out[(g << 5) + vs + j] = row[vs + j] - lse;
}

extern "C" void kernel_launch(void* const* d_in, const int* in_sizes, int n_in,
                              void* d_out, int out_size, void* d_ws, size_t ws_size,
                              hipStream_t stream) {
    const float* x = (const float*)d_in[0];
    const int* ei = (const int*)d_in[1];
    const int* batch = (const int*)d_in[2];
    const float* W1 = (const float*)d_in[3];
    const float* root1 = (const float*)d_in[4];
    const float* b1 = (const float*)d_in[5];
    const float* W2 = (const float*)d_in[6];
    const float* root2 = (const float*)d_in[7];
    const float* b2 = (const float*)d_in[8];
    const float* Wh = (const float*)d_in[9];
    const float* bh = (const float*)d_in[10];
    const float* Wc = (const float*)d_in[11];
    const float* bc = (const float*)d_in[12];
    const float* Wo = (const float*)d_in[13];
    const float* bo = (const float*)d_in[14];
    float* out = (float*)d_out;

    const int N = in_sizes[0] / 64;
    const int E = in_sizes[1] / 2;
    const int* srcp = ei;
    const int* dstp = ei + E;
    const int BINS = (N + (1 << RB) - 1) >> RB;

    char* ws = (char*)d_ws;
    size_t off = 0;
    auto alloc = [&](size_t bytes) -> void* {
        void* p = ws + off;
        off += (bytes + 255) & ~(size_t)255;
        return p;
    };
    int* pstart = (int*)alloc((size_t)N * 4);
    int* degarr = (int*)alloc((size_t)N * 4);
    int* bucket = (int*)alloc(((size_t)BINS * BCAP + 256) * 4);
    unsigned int* coarse = (unsigned int*)alloc((size_t)BINS * CAP * 4);
    unsigned short* h1 = (unsigned short*)alloc((size_t)N * 64 * 2);
    unsigned short* h2 = (unsigned short*)alloc((size_t)N * 64 * 2);
    unsigned char* xw8 = (unsigned char*)alloc((size_t)(N + 1) * 64);    // layer1 fp8
    unsigned char* xw8b = (unsigned char*)alloc((size_t)(N + 1) * 64);   // layer2 fp8
    unsigned short* xrb = (unsigned short*)alloc((size_t)N * 64 * 2);
    unsigned short* xrb2 = (unsigned short*)alloc((size_t)N * 64 * 2);
    int* gcur = (int*)alloc(MAXBINS * 4);        // 1024 B, 256-aligned
    float* gsum = (float*)alloc(4096 * 4);       // contiguous after gcur

    const int nbBin = (E + CHUNK - 1) / CHUNK;

    // one memset covers gcur (1 KiB) + gsum (16 KiB): contiguous in ws.
    hipMemsetAsync(gcur, 0, MAXBINS * 4 + 4096 * 4, stream);
    bin_gemm1<<<nbBin + 1024, 256, 0, stream>>>(srcp, dstp, coarse, gcur, E, BINS, nbBin,
                                                x, W1, root1, b1, xw8, xrb, N);
    finalize_csr<<<BINS, 256, 0, stream>>>(coarse, gcur, bucket, pstart, degarr, N, BINS);
    aggregate<<<4096, 256, 0, stream>>>(xw8, xrb, pstart, degarr, bucket, h1, N);
    gemm_xwr2<<<1024, 256, 0, stream>>>(h1, W2, root2, b2, xw8b, xrb2, N);
    aggregate<<<4096, 256, 0, stream>>>(xw8b, xrb2, pstart, degarr, bucket, h2, N);
    pool_kernel<<<256, 256, 0, stream>>>(h2, batch, gsum, N);
    head_kernel<<<1, 256, 0, stream>>>(gsum, batch, Wh, bh, Wc, bc, Wo, bo, out, N);
}

// Round 7
// 245.614 us; speedup vs baseline: 1.0094x; 1.0094x over previous
//
#include <hip/hip_runtime.h>
#include <hip/hip_bf16.h>

// FEAT=EMB=HID=64, VOCAB=32, N_GRAPHS=64. N,E from in_sizes.
// R6: transform-first. R7: binned CSR. R9: padded CSR + mask-free gather.
// R11: fp8 e4m3 gather table (64B rows = 1 line), quarter-wave dword gather.
// R13/R14: gemm1 fused into binning kernel; B-frags self-built from fp32.
// R17: head_kernel rewrite (LDS-staged weights, reg-blocked, parallel softmax).
// R18 REVERTED (fusions serialized 16 nodes/wave -> latency-bound 137us).
// R19: two-node-interleaved aggregate (8 gather loads in flight). 272->264us.
// R20 REVERTED to 2-node (4-node = +13% padded work, no latency win left).
// R21: per-node wave-uniform tail guards + 32-bit saddr. 275.6->246.5us.
// R22: f32x2 pk-add accumulators; true-degree bucket mask; finalize pad loop
// deleted. Neutral (246.5->247.9) — aggregate is gather-latency/BW-bound,
// not VALU-bound. Kept (bit-identical, simpler).
// R23: CHUNK 8192->4096 in bin_gemm1 — static LDS 45KB->25KB raises the
// occupancy ceiling 3->6 blocks/CU for BOTH branches (gemm branch uses no
// LDS but paid the allocation), and binning parallelism 196->391 blocks.
// aggregate: xrb epilogue loads hoisted before the gather loop (latency
// hidden under gathers). No math changes anywhere.

typedef __attribute__((ext_vector_type(8))) short short8;
typedef __attribute__((ext_vector_type(4))) float f32x4;
typedef __attribute__((ext_vector_type(2))) float f32x2;

#define RB 9            // 512 nodes per coarse bin
#define MAXBINS 256     // N <= 131072
#define CAP 12288       // coarse per-bin capacity
#define BCAP 14336      // padded per-bin bucket capacity
#define CHUNK 4096      // edges per bin block (R23: was 8192)

__device__ inline float bf2f(unsigned short h) {
    return __uint_as_float(((unsigned int)h) << 16);
}
__device__ inline float bflo(unsigned int u) { return __uint_as_float(u << 16); }
__device__ inline float bfhi(unsigned int u) { return __uint_as_float(u & 0xffff0000u); }
__device__ inline unsigned short f2bf(float f) {
    unsigned int u = __float_as_uint(f);
    u = (u + 0x7fffu + ((u >> 16) & 1u)) >> 16;  // RNE
    return (unsigned short)u;
}

// Self-build MFMA B-fragments from fp32 W (cols 0..63) and R (cols 64..127).
__device__ inline void build_bfrag(const float* __restrict__ W,
                                   const float* __restrict__ R,
                                   int q, int mm, short8 bfrag[8][2]) {
#pragma unroll
    for (int t = 0; t < 8; ++t) {
        const int n = t * 16 + mm;
        const float* P = (n < 64) ? (W + n) : (R + n - 64);
#pragma unroll
        for (int c = 0; c < 2; ++c) {
#pragma unroll
            for (int j = 0; j < 8; ++j) {
                const int k = c * 32 + q * 8 + j;
                bfrag[t][c][j] = (short)f2bf(P[k * 64]);
            }
        }
    }
}

// fp8 epilogue store: lanes mm%4==0 pack 4 n-columns into one dword.
__device__ inline void store_xw_fp8(unsigned char* __restrict__ xw8, int rowbase, int q,
                                    int t, int mm, const f32x4& accT, int N) {
#pragma unroll
    for (int r = 0; r < 4; ++r) {
        const float v0 = accT[r];
        const float v1 = __shfl_down(v0, 1);
        const float v2 = __shfl_down(v0, 2);
        const float v3 = __shfl_down(v0, 3);
        const int orow = rowbase + q * 4 + r;
        if (!(mm & 3) && orow < N) {
            unsigned int u = (unsigned int)__builtin_amdgcn_cvt_pk_fp8_f32(v0, v1, 0, false);
            u = (unsigned int)__builtin_amdgcn_cvt_pk_fp8_f32(v2, v3, (int)u, true);
            *(unsigned int*)&xw8[(size_t)orow * 64 + t * 16 + mm] = u;
        }
    }
}

// ---------------- K1: bin edges (blocks [0,nbBin)) + gemm1 (rest) -----------
__global__ __launch_bounds__(256) void bin_gemm1(const int* __restrict__ src,
                                                 const int* __restrict__ dst,
                                                 unsigned int* __restrict__ coarse,
                                                 int* __restrict__ gcur,
                                                 int E, int BINS, int nbBin,
                                                 const float* __restrict__ x,
                                                 const float* __restrict__ W1,
                                                 const float* __restrict__ R1,
                                                 const float* __restrict__ bias,
                                                 unsigned char* __restrict__ xw8,
                                                 unsigned short* __restrict__ xrb,
                                                 int N) {
    __shared__ int cnt[MAXBINS];
    __shared__ int incl[MAXBINS];
    __shared__ int bstart[MAXBINS];
    __shared__ int bcur[MAXBINS];
    __shared__ int gbase[MAXBINS];
    __shared__ unsigned int stage[CHUNK];
    __shared__ unsigned char binOf[CHUNK];

    const int tid = threadIdx.x;
    if (blockIdx.x >= (unsigned)nbBin) {
        // ---- gemm1 branch: xw8/xrb = x @ [W1|R1] (+b1 in R half) ----
        const int gb = blockIdx.x - nbBin;
        if (gb == 0 && tid < 16)  // zero fp8 row N (dummy target)
            *(unsigned int*)&xw8[(size_t)N * 64 + tid * 4] = 0u;

        const int lane = tid & 63;
        const int q = lane >> 4;
        const int mm = lane & 15;

        short8 bfrag[8][2];
        build_bfrag(W1, R1, q, mm, bfrag);
        float bv[4];
#pragma unroll
        for (int tt = 0; tt < 4; ++tt) bv[tt] = bias[tt * 16 + mm];

        const int wid = tid >> 6;
        const int gw = gb * 4 + wid;
        const int nw = 1024 * 4;
        const int ntiles = N >> 4;

        for (int tile = gw; tile < ntiles; tile += nw) {
            const int row0 = tile << 4;
            const float* ap = &x[(size_t)(row0 + mm) * 64 + q * 8];
            const float4 f0 = *(const float4*)ap;
            const float4 f1 = *(const float4*)(ap + 4);
            const float4 f2 = *(const float4*)(ap + 32);
            const float4 f3 = *(const float4*)(ap + 36);
            short8 a0, a1;
            a0[0] = (short)f2bf(f0.x); a0[1] = (short)f2bf(f0.y);
            a0[2] = (short)f2bf(f0.z); a0[3] = (short)f2bf(f0.w);
            a0[4] = (short)f2bf(f1.x); a0[5] = (short)f2bf(f1.y);
            a0[6] = (short)f2bf(f1.z); a0[7] = (short)f2bf(f1.w);
            a1[0] = (short)f2bf(f2.x); a1[1] = (short)f2bf(f2.y);
            a1[2] = (short)f2bf(f2.z); a1[3] = (short)f2bf(f2.w);
            a1[4] = (short)f2bf(f3.x); a1[5] = (short)f2bf(f3.y);
            a1[6] = (short)f2bf(f3.z); a1[7] = (short)f2bf(f3.w);
            f32x4 acc[8];
#pragma unroll
            for (int t = 0; t < 8; ++t) {
                acc[t] = (f32x4){0.f, 0.f, 0.f, 0.f};
                acc[t] = __builtin_amdgcn_mfma_f32_16x16x32_bf16(a0, bfrag[t][0], acc[t], 0, 0, 0);
                acc[t] = __builtin_amdgcn_mfma_f32_16x16x32_bf16(a1, bfrag[t][1], acc[t], 0, 0, 0);
            }
#pragma unroll
            for (int t = 0; t < 4; ++t) store_xw_fp8(xw8, row0, q, t, mm, acc[t], N);
#pragma unroll
            for (int t = 4; t < 8; ++t) {
#pragma unroll
                for (int r = 0; r < 4; ++r) {
                    const float v = acc[t][r] + bv[t - 4];
                    const float vn = __shfl_down(v, 1);
                    if (!(mm & 1)) {
                        const unsigned int u = (unsigned int)f2bf(v) | ((unsigned int)f2bf(vn) << 16);
                        *(unsigned int*)&xrb[(size_t)(row0 + q * 4 + r) * 64 + (t - 4) * 16 + mm] = u;
                    }
                }
            }
        }
        return;
    }

    // ---- binning branch (16 edges/thread at CHUNK=4096) ----
    const int chunk0 = blockIdx.x * CHUNK;
    int myS[16], myD[16];
#pragma unroll
    for (int k = 0; k < 16; ++k) {
        const int idx = chunk0 + k * 256 + tid;
        if (idx < E) { myS[k] = src[idx]; myD[k] = dst[idx]; }
        else myD[k] = -1;
    }
    cnt[tid] = 0;
    __syncthreads();
#pragma unroll
    for (int k = 0; k < 16; ++k)
        if (myD[k] >= 0) atomicAdd(&cnt[myD[k] >> RB], 1);
    __syncthreads();
    incl[tid] = cnt[tid];
    __syncthreads();
    for (int off = 1; off < 256; off <<= 1) {
        int t = (tid >= off) ? incl[tid - off] : 0;
        __syncthreads();
        incl[tid] += t;
        __syncthreads();
    }
    bstart[tid] = incl[tid] - cnt[tid];
    bcur[tid] = incl[tid] - cnt[tid];
    __syncthreads();
#pragma unroll
    for (int k = 0; k < 16; ++k) {
        if (myD[k] >= 0) {
            const int b = myD[k] >> RB;
            const int pos = atomicAdd(&bcur[b], 1);
            stage[pos] = (unsigned int)myS[k] | ((unsigned int)(myD[k] & ((1 << RB) - 1)) << 17);
            binOf[pos] = (unsigned char)b;
        }
    }
    __syncthreads();
    if (tid < BINS && cnt[tid] > 0)
        gbase[tid] = tid * CAP + atomicAdd(&gcur[tid], cnt[tid]);
    __syncthreads();
    int total = E - chunk0;
    if (total > CHUNK) total = CHUNK;
    for (int idx = tid; idx < total; idx += 256) {
        const int b = binOf[idx];
        coarse[gbase[b] + (idx - bstart[b])] = stage[idx];
    }
}

// ---------------- K2: finalize padded CSR (one block per bin) ---------------
// R22: pad-tail writes removed — aggregate masks bucket loads by TRUE degree,
// so pad slots are never read. Offsets stay 16-padded for group alignment.
__global__ __launch_bounds__(256) void finalize_csr(const unsigned int* __restrict__ coarse,
                                                    const int* __restrict__ gcur,
                                                    int* __restrict__ bucket,
                                                    int* __restrict__ pstart,
                                                    int* __restrict__ degarr,
                                                    int N, int BINS) {
    __shared__ int ncnt[512];
    __shared__ int pexcl[512];
    __shared__ int ncur[512];
    __shared__ int s2[256];

    const int tid = threadIdx.x;
    const int b = blockIdx.x;
    const int cb = gcur[b];
    const int base = b * BCAP;
    const unsigned int* reg = coarse + (size_t)b * CAP;
    const int node0 = b << RB;
    int nloc = N - node0;
    if (nloc > 512) nloc = 512;

    ncnt[tid] = 0; ncnt[tid + 256] = 0;
    __syncthreads();
    for (int idx = tid; idx < cb; idx += 256)
        atomicAdd(&ncnt[reg[idx] >> 17], 1);
    __syncthreads();
    const int p0 = (ncnt[2 * tid] + 15) & ~15;
    const int p1 = (ncnt[2 * tid + 1] + 15) & ~15;
    s2[tid] = p0 + p1;
    __syncthreads();
    for (int off = 1; off < 256; off <<= 1) {
        int t = (tid >= off) ? s2[tid - off] : 0;
        __syncthreads();
        s2[tid] += t;
        __syncthreads();
    }
    const int pairExcl = s2[tid] - (p0 + p1);
    pexcl[2 * tid] = pairExcl;
    pexcl[2 * tid + 1] = pairExcl + p0;
    ncur[2 * tid] = pairExcl;
    ncur[2 * tid + 1] = pairExcl + p0;
    __syncthreads();
    for (int i = tid; i < nloc; i += 256) {
        pstart[node0 + i] = base + pexcl[i];
        degarr[node0 + i] = ncnt[i];
    }
    for (int idx = tid; idx < cb; idx += 256) {
        const unsigned int e = reg[idx];
        const int p = atomicAdd(&ncur[e >> 17], 1);
        bucket[base + p] = (int)(e & 0x1FFFFu);
    }
}

// ---------------- K3/K5: aggregate: out = relu(mean_j xW[j] + xRb[i]) -------
// R21: two nodes (i, i+nw) interleaved; per-node wave-uniform tail guards;
// 32-bit saddr addressing. R22: f32x2 pk-add accumulators; true-degree mask.
// R23: xrb loads hoisted before the gather loop (latency hidden).
__global__ __launch_bounds__(256) void aggregate(const unsigned char* __restrict__ xw8,
                                                 const unsigned short* __restrict__ xrb,
                                                 const int* __restrict__ pstart,
                                                 const int* __restrict__ degarr,
                                                 const int* __restrict__ bucket,
                                                 unsigned short* __restrict__ outb,
                                                 int N) {
    const int lane = threadIdx.x & 63;
    const int quarter = lane >> 4;
    const int fl = lane & 15;
    const int wid = threadIdx.x >> 6;
    const int gw = blockIdx.x * 4 + wid;
    const int nw = gridDim.x * 4;
    const unsigned flo = (unsigned)(fl << 2);

    for (int i = gw; i < N; i += 2 * nw) {
        const int iA = i;
        const int iB = i + nw;
        const bool hasB = iB < N;
        const int r0A = pstart[iA];
        const int dgA = degarr[iA];
        int r0B = r0A, dgB = 0;
        if (hasB) { r0B = pstart[iB]; dgB = degarr[iB]; }
        const int pdA = (dgA + 15) & ~15;
        const int pdB = (dgB + 15) & ~15;
        const int pdM = pdA > pdB ? pdA : pdB;

        // R23: issue epilogue root-term loads early; consumed after gathers.
        uint2 urA = {0u, 0u}, urB = {0u, 0u};
        if (quarter == 0) {
            urA = *(const uint2*)&xrb[(size_t)iA * 64 + fl * 4];
            if (hasB) urB = *(const uint2*)&xrb[(size_t)iB * 64 + fl * 4];
        }

        f32x2 aAlo = {0.f, 0.f}, aAhi = {0.f, 0.f};
        f32x2 aBlo = {0.f, 0.f}, aBhi = {0.f, 0.f};
        for (int base = 0; base < pdM; base += 64) {
            const int remA = pdA - base;     // padded remainder: group guard
            const int remB = pdB - base;
            const int trmA = dgA - base;     // true remainder: bucket mask
            const int trmB = dgB - base;
            int sA = N, sB = N;
            if (trmA > 0 && lane < trmA)
                sA = *(const int*)((const char*)bucket + ((unsigned)(r0A + base + lane) << 2));
            if (trmB > 0 && lane < trmB)
                sB = *(const int*)((const char*)bucket + ((unsigned)(r0B + base + lane) << 2));
            const int mxA = remA < 64 ? remA : 64;
            const int mxB = remB < 64 ? remB : 64;
            int mx = pdM - base;
            if (mx > 64) mx = 64;
            for (int t = 0; t < mx; t += 16) {
                const bool doA = t < mxA;   // wave-uniform
                const bool doB = t < mxB;   // wave-uniform
                unsigned int uA[4], uB[4];
                if (doA) {
#pragma unroll
                    for (int p = 0; p < 4; ++p) {
                        const unsigned rr = (unsigned)__shfl(sA, t + 4 * p + quarter);
                        uA[p] = *(const unsigned int*)(xw8 + ((rr << 6) | flo));
                    }
                }
                if (doB) {
#pragma unroll
                    for (int p = 0; p < 4; ++p) {
                        const unsigned rr = (unsigned)__shfl(sB, t + 4 * p + quarter);
                        uB[p] = *(const unsigned int*)(xw8 + ((rr << 6) | flo));
                    }
                }
                if (doA) {
#pragma unroll
                    for (int p = 0; p < 4; ++p) {
                        aAlo += __builtin_amdgcn_cvt_pk_f32_fp8(uA[p], false);
                        aAhi += __builtin_amdgcn_cvt_pk_f32_fp8(uA[p], true);
                    }
                }
                if (doB) {
#pragma unroll
                    for (int p = 0; p < 4; ++p) {
                        aBlo += __builtin_amdgcn_cvt_pk_f32_fp8(uB[p], false);
                        aBhi += __builtin_amdgcn_cvt_pk_f32_fp8(uB[p], true);
                    }
                }
            }
        }
        float aA0 = aAlo.x, aA1 = aAlo.y, aA2 = aAhi.x, aA3 = aAhi.y;
        float aB0 = aBlo.x, aB1 = aBlo.y, aB2 = aBhi.x, aB3 = aBhi.y;
        aA0 += __shfl_xor(aA0, 16); aA1 += __shfl_xor(aA1, 16);
        aA2 += __shfl_xor(aA2, 16); aA3 += __shfl_xor(aA3, 16);
        aA0 += __shfl_xor(aA0, 32); aA1 += __shfl_xor(aA1, 32);
        aA2 += __shfl_xor(aA2, 32); aA3 += __shfl_xor(aA3, 32);
        aB0 += __shfl_xor(aB0, 16); aB1 += __shfl_xor(aB1, 16);
        aB2 += __shfl_xor(aB2, 16); aB3 += __shfl_xor(aB3, 16);
        aB0 += __shfl_xor(aB0, 32); aB1 += __shfl_xor(aB1, 32);
        aB2 += __shfl_xor(aB2, 32); aB3 += __shfl_xor(aB3, 32);

        if (quarter == 0) {
            const float invA = 1.0f / (float)(dgA > 0 ? dgA : 1);
            const float o0 = fmaxf(aA0 * invA + bflo(urA.x), 0.f);
            const float o1 = fmaxf(aA1 * invA + bfhi(urA.x), 0.f);
            const float o2 = fmaxf(aA2 * invA + bflo(urA.y), 0.f);
            const float o3 = fmaxf(aA3 * invA + bfhi(urA.y), 0.f);
            uint2 w;
            w.x = (unsigned int)f2bf(o0) | ((unsigned int)f2bf(o1) << 16);
            w.y = (unsigned int)f2bf(o2) | ((unsigned int)f2bf(o3) << 16);
            *(uint2*)&outb[(size_t)iA * 64 + fl * 4] = w;
            if (hasB) {
                const float invB = 1.0f / (float)(dgB > 0 ? dgB : 1);
                const float p0 = fmaxf(aB0 * invB + bflo(urB.x), 0.f);
                const float p1 = fmaxf(aB1 * invB + bfhi(urB.x), 0.f);
                const float p2 = fmaxf(aB2 * invB + bflo(urB.y), 0.f);
                const float p3 = fmaxf(aB3 * invB + bfhi(urB.y), 0.f);
                uint2 w2;
                w2.x = (unsigned int)f2bf(p0) | ((unsigned int)f2bf(p1) << 16);
                w2.y = (unsigned int)f2bf(p2) | ((unsigned int)f2bf(p3) << 16);
                *(uint2*)&outb[(size_t)iB * 64 + fl * 4] = w2;
            }
        }
    }
}

// ---------------- K4: gemm layer 2 (bf16 A from h1, self-built B) -----------
__global__ __launch_bounds__(256) void gemm_xwr2(const unsigned short* __restrict__ xin,
                                                 const float* __restrict__ W2,
                                                 const float* __restrict__ R2,
                                                 const float* __restrict__ bias,
                                                 unsigned char* __restrict__ xw8,
                                                 unsigned short* __restrict__ xrb,
                                                 int M) {
    if (blockIdx.x == 0 && threadIdx.x < 16)
        *(unsigned int*)&xw8[(size_t)M * 64 + threadIdx.x * 4] = 0u;

    const int lane = threadIdx.x & 63;
    const int q = lane >> 4;
    const int mm = lane & 15;

    short8 bfrag[8][2];
    build_bfrag(W2, R2, q, mm, bfrag);
    float bv[4];
#pragma unroll
    for (int tt = 0; tt < 4; ++tt) bv[tt] = bias[tt * 16 + mm];

    const int wid = threadIdx.x >> 6;
    const int gw = blockIdx.x * 4 + wid;
    const int nw = gridDim.x * 4;
    const int ntiles = M >> 4;

    for (int tile = gw; tile < ntiles; tile += nw) {
        const int row0 = tile << 4;
        const short8 a0 = *(const short8*)&xin[(size_t)(row0 + mm) * 64 + q * 8];
        const short8 a1 = *(const short8*)&xin[(size_t)(row0 + mm) * 64 + 32 + q * 8];
        f32x4 acc[8];
#pragma unroll
        for (int t = 0; t < 8; ++t) {
            acc[t] = (f32x4){0.f, 0.f, 0.f, 0.f};
            acc[t] = __builtin_amdgcn_mfma_f32_16x16x32_bf16(a0, bfrag[t][0], acc[t], 0, 0, 0);
            acc[t] = __builtin_amdgcn_mfma_f32_16x16x32_bf16(a1, bfrag[t][1], acc[t], 0, 0, 0);
        }
#pragma unroll
        for (int t = 0; t < 4; ++t) store_xw_fp8(xw8, row0, q, t, mm, acc[t], M);
#pragma unroll
        for (int t = 4; t < 8; ++t) {
#pragma unroll
            for (int r = 0; r < 4; ++r) {
                const float v = acc[t][r] + bv[t - 4];
                const float vn = __shfl_down(v, 1);
                if (!(mm & 1)) {
                    const unsigned int u = (unsigned int)f2bf(v) | ((unsigned int)f2bf(vn) << 16);
                    *(unsigned int*)&xrb[(size_t)(row0 + q * 4 + r) * 64 + (t - 4) * 16 + mm] = u;
                }
            }
        }
    }
}

// ---------------- K6: pooling (4 blocks per graph, atomic sums) -------------
__global__ __launch_bounds__(256) void pool_kernel(const unsigned short* __restrict__ h,
                                                   const int* __restrict__ batch,
                                                   float* __restrict__ gsum, int N) {
    __shared__ float red[16][64];
    __shared__ int bnds[2];
    const int gph = blockIdx.x >> 2;
    const int part = blockIdx.x & 3;
    if (threadIdx.x < 2) {
        const int target = gph + threadIdx.x;
        int lo = 0, hi = N;
        while (lo < hi) {
            int mid = (lo + hi) >> 1;
            if (batch[mid] < target) lo = mid + 1; else hi = mid;
        }
        bnds[threadIdx.x] = lo;
    }
    __syncthreads();
    const int r0 = bnds[0], tot = bnds[1] - bnds[0];
    const int pr0 = r0 + (tot * part) / 4;
    const int pr1 = r0 + (tot * (part + 1)) / 4;
    const int f = threadIdx.x & 15;
    const int r = threadIdx.x >> 4;
    float4 acc = {0.f, 0.f, 0.f, 0.f};
    for (int row = pr0 + r; row < pr1; row += 16) {
        const ushort4 v = *(const ushort4*)&h[(size_t)row * 64 + f * 4];
        acc.x += bf2f(v.x); acc.y += bf2f(v.y);
        acc.z += bf2f(v.z); acc.w += bf2f(v.w);
    }
    red[r][f * 4 + 0] = acc.x; red[r][f * 4 + 1] = acc.y;
    red[r][f * 4 + 2] = acc.z; red[r][f * 4 + 3] = acc.w;
    __syncthreads();
    if (threadIdx.x < 64) {
        float s = 0.f;
        for (int j = 0; j < 16; ++j) s += red[j][threadIdx.x];
        atomicAdd(&gsum[gph * 64 + threadIdx.x], s);
    }
}

// ---------------- K7: heads (normalize gsum by counts; R18-verified) --------
__global__ __launch_bounds__(256) void head_kernel(const float* __restrict__ gsum,
                                                   const int* __restrict__ batch,
                                                   const float* __restrict__ Wh,
                                                   const float* __restrict__ bh,
                                                   const float* __restrict__ Wc,
                                                   const float* __restrict__ bc,
                                                   const float* __restrict__ Wo,
                                                   const float* __restrict__ bo,
                                                   float* __restrict__ out, int N) {
    __shared__ float pm[4096];   // pooled; reused for lg[2048] in phase 2/3
    __shared__ float Ws[4096];   // Wh; reused for Wo[2048] in phase 2
    __shared__ float Cs[4096];   // Wc
    __shared__ float hid[4096];
    __shared__ int bnds[65];
    const int t = threadIdx.x;

    // Phase 0a: graph bounds via binary search on sorted batch.
    if (t < 65) {
        int lo = 0, hi = N;
        while (lo < hi) {
            int mid = (lo + hi) >> 1;
            if (batch[mid] < t) lo = mid + 1; else hi = mid;
        }
        bnds[t] = lo;
    }
    __syncthreads();
    // Phase 0b: stage pooled (= gsum/cnt) + Wh + Wc (float4, coalesced).
    for (int idx = t; idx < 1024; idx += 256) {
        const int g = idx >> 4;
        const int c = bnds[g + 1] - bnds[g];
        const float inv = 1.0f / (float)(c > 0 ? c : 1);
        float4 v = ((const float4*)gsum)[idx];
        v.x *= inv; v.y *= inv; v.z *= inv; v.w *= inv;
        ((float4*)pm)[idx] = v;
        ((float4*)Ws)[idx] = ((const float4*)Wh)[idx];
        ((float4*)Cs)[idx] = ((const float4*)Wc)[idx];
    }
    __syncthreads();

    // Phase 1: hidden/cell. Wave w owns 16 graphs, lane l owns col o=l.
    const int w = t >> 6;
    const int l = t & 63;
    const float bhv = bh[l], bcv = bc[l];
    float ah[16], ac[16];
#pragma unroll
    for (int i = 0; i < 16; ++i) { ah[i] = bhv; ac[i] = bcv; }
    const float* pmw = pm + ((w << 4) << 6);
#pragma unroll 4
    for (int k = 0; k < 64; ++k) {
        const float wv = Ws[(k << 6) + l];
        const float cv = Cs[(k << 6) + l];
#pragma unroll
        for (int i = 0; i < 16; ++i) {
            const float p = pmw[(i << 6) + k];
            ah[i] = fmaf(p, wv, ah[i]);
            ac[i] = fmaf(p, cv, ac[i]);
        }
    }
#pragma unroll
    for (int i = 0; i < 16; ++i) {
        const int g = (w << 4) + i;
        hid[(g << 6) + l] = ah[i];
        out[2048 + (g << 6) + l] = ah[i];
        out[6144 + (g << 6) + l] = ac[i];
    }
    __syncthreads();
    // Stage Wo over Ws (reads of Ws are done).
    for (int idx = t; idx < 512; idx += 256)
        ((float4*)Ws)[idx] = ((const float4*)Wo)[idx];
    __syncthreads();

    // Phase 2: logits[g][v] = hid[g] . Wo[:,v] + bo[v]; 8 graphs per thread.
    const int v = l & 31;
    const int gh = l >> 5;                // 0 or 1
    const int g0 = ((w << 1) + gh) << 3;  // 8 consecutive graphs
    const float bov = bo[v];
    float lgacc[8];
#pragma unroll
    for (int i = 0; i < 8; ++i) lgacc[i] = bov;
#pragma unroll 4
    for (int k = 0; k < 64; ++k) {
        const float wv = Ws[(k << 5) + v];
#pragma unroll
        for (int i = 0; i < 8; ++i)
            lgacc[i] = fmaf(hid[((g0 + i) << 6) + k], wv, lgacc[i]);
    }
    float* lg = pm;  // reuse pm (pooled reads are done)
#pragma unroll
    for (int i = 0; i < 8; ++i) lg[((g0 + i) << 5) + v] = lgacc[i];
    __syncthreads();

    // Phase 3: log_softmax, 4 threads per graph (8 vocab each), shfl reduce.
    const int g = t >> 2;
    const int vs = (t & 3) << 3;
    const float* row = lg + (g << 5);
    float mx = -3.4e38f;
#pragma unroll
    for (int j = 0; j < 8; ++j) mx = fmaxf(mx, row[vs + j]);
    mx = fmaxf(mx, __shfl_xor(mx, 1));
    mx = fmaxf(mx, __shfl_xor(mx, 2));
    float s = 0.f;
#pragma unroll
    for (int j = 0; j < 8; ++j) s += __expf(row[vs + j] - mx);
    s += __shfl_xor(s, 1);
    s += __shfl_xor(s, 2);
    const float lse = mx + __logf(s);
#pragma unroll
    for (int j = 0; j < 8; ++j) out[(g << 5) + vs + j] = row[vs + j] - lse;
}

extern "C" void kernel_launch(void* const* d_in, const int* in_sizes, int n_in,
                              void* d_out, int out_size, void* d_ws, size_t ws_size,
                              hipStream_t stream) {
    const float* x = (const float*)d_in[0];
    const int* ei = (const int*)d_in[1];
    const int* batch = (const int*)d_in[2];
    const float* W1 = (const float*)d_in[3];
    const float* root1 = (const float*)d_in[4];
    const float* b1 = (const float*)d_in[5];
    const float* W2 = (const float*)d_in[6];
    const float* root2 = (const float*)d_in[7];
    const float* b2 = (const float*)d_in[8];
    const float* Wh = (const float*)d_in[9];
    const float* bh = (const float*)d_in[10];
    const float* Wc = (const float*)d_in[11];
    const float* bc = (const float*)d_in[12];
    const float* Wo = (const float*)d_in[13];
    const float* bo = (const float*)d_in[14];
    float* out = (float*)d_out;

    const int N = in_sizes[0] / 64;
    const int E = in_sizes[1] / 2;
    const int* srcp = ei;
    const int* dstp = ei + E;
    const int BINS = (N + (1 << RB) - 1) >> RB;

    char* ws = (char*)d_ws;
    size_t off = 0;
    auto alloc = [&](size_t bytes) -> void* {
        void* p = ws + off;
        off += (bytes + 255) & ~(size_t)255;
        return p;
    };
    int* pstart = (int*)alloc((size_t)N * 4);
    int* degarr = (int*)alloc((size_t)N * 4);
    int* bucket = (int*)alloc(((size_t)BINS * BCAP + 256) * 4);
    unsigned int* coarse = (unsigned int*)alloc((size_t)BINS * CAP * 4);
    unsigned short* h1 = (unsigned short*)alloc((size_t)N * 64 * 2);
    unsigned short* h2 = (unsigned short*)alloc((size_t)N * 64 * 2);
    unsigned char* xw8 = (unsigned char*)alloc((size_t)(N + 1) * 64);    // layer1 fp8
    unsigned char* xw8b = (unsigned char*)alloc((size_t)(N + 1) * 64);   // layer2 fp8
    unsigned short* xrb = (unsigned short*)alloc((size_t)N * 64 * 2);
    unsigned short* xrb2 = (unsigned short*)alloc((size_t)N * 64 * 2);
    int* gcur = (int*)alloc(MAXBINS * 4);        // 1024 B, 256-aligned
    float* gsum = (float*)alloc(4096 * 4);       // contiguous after gcur

    const int nbBin = (E + CHUNK - 1) / CHUNK;

    // one memset covers gcur (1 KiB) + gsum (16 KiB): contiguous in ws.
    hipMemsetAsync(gcur, 0, MAXBINS * 4 + 4096 * 4, stream);
    bin_gemm1<<<nbBin + 1024, 256, 0, stream>>>(srcp, dstp, coarse, gcur, E, BINS, nbBin,
                                                x, W1, root1, b1, xw8, xrb, N);
    finalize_csr<<<BINS, 256, 0, stream>>>(coarse, gcur, bucket, pstart, degarr, N, BINS);
    aggregate<<<4096, 256, 0, stream>>>(xw8, xrb, pstart, degarr, bucket, h1, N);
    gemm_xwr2<<<1024, 256, 0, stream>>>(h1, W2, root2, b2, xw8b, xrb2, N);
    aggregate<<<4096, 256, 0, stream>>>(xw8b, xrb2, pstart, degarr, bucket, h2, N);
    pool_kernel<<<256, 256, 0, stream>>>(h2, batch, gsum, N);
    head_kernel<<<1, 256, 0, stream>>>(gsum, batch, Wh, bh, Wc, bc, Wo, bo, out, N);
}